// Round 10
// baseline (149.598 us; speedup 1.0000x reference)
//
#include <hip/hip_runtime.h>
#include <hip/hip_bf16.h>

#define N_Z 16384
#define M_E 4096
#define DIM 256
#define NB5 1024                      // wise buckets (monotone map)
#define BMIN (-6.0f)
#define SCALE5 ((float)NB5 / 12.0f)

typedef __bf16 bf16x8 __attribute__((ext_vector_type(8)));
typedef float f32x4 __attribute__((ext_vector_type(4)));

__device__ __forceinline__ unsigned short f2bf(float f) {
  unsigned u = __float_as_uint(f);
  u = (u + 0x7FFFu + ((u >> 16) & 1u)) >> 16;
  return (unsigned short)u;
}

__device__ __forceinline__ void gl2lds16(const void* g, void* s) {
  __builtin_amdgcn_global_load_lds(
      (const __attribute__((address_space(1))) unsigned*)g,
      (__attribute__((address_space(3))) unsigned*)s, 16, 0, 0);
}

// order-preserving float<->uint map
__device__ __forceinline__ unsigned fmap(float f) {
  unsigned u = __float_as_uint(f);
  return (u & 0x80000000u) ? ~u : (u | 0x80000000u);
}
__device__ __forceinline__ float funmap(unsigned u) {
  return __uint_as_float((u & 0x80000000u) ? (u ^ 0x80000000u) : ~u);
}
// MONOTONE bucket map (v<w => bucket(v)<=bucket(w)); exactness needs only monotonicity
__device__ __forceinline__ int bucket5(float v) {
  int b = (int)((v - BMIN) * SCALE5);
  return min(max(b, 0), NB5 - 1);
}

// ---------------- init ----------------
__global__ void init_kernel(unsigned* __restrict__ d2min, float* __restrict__ wise_part,
                            float* __restrict__ z2, float* __restrict__ e2) {
  int i = blockIdx.x * blockDim.x + threadIdx.x;
  if (i < M_E) d2min[i] = 0x7F800000u;
  if (i < 64) wise_part[i] = 0.0f;
  if (i < N_Z) z2[i] = 0.0f;
  if (i < M_E) e2[i] = 0.0f;
}

// ---------------- fused prep: read once -> bf16 copy + transpose + row sq-norm ----------------
__global__ void prep_kernel(const float* __restrict__ in, float* __restrict__ outT,
                            unsigned short* __restrict__ outB, float* __restrict__ rsum, int R) {
  __shared__ float tile[32][33];
  int r0 = blockIdx.x * 32, c0 = blockIdx.y * 32;
  int tx = threadIdx.x, ty = threadIdx.y;
#pragma unroll
  for (int i = 0; i < 4; ++i) {
    int rr = ty + 8 * i;
    float v = in[(size_t)(r0 + rr) * DIM + c0 + tx];
    tile[rr][tx] = v;
    outB[(size_t)(r0 + rr) * DIM + c0 + tx] = f2bf(v);
    float s = v * v;
#pragma unroll
    for (int o = 1; o < 32; o <<= 1) s += __shfl_xor(s, o);  // xor<32: stays in row group
    if (tx == 0) atomicAdd(&rsum[r0 + rr], s);
  }
  __syncthreads();
#pragma unroll
  for (int i = 0; i < 4; ++i)
    outT[(size_t)(c0 + ty + 8 * i) * R + r0 + tx] = tile[tx][ty + 8 * i];
}

// ---------------- fused bf16 GEMM (z . e^T) + min over n, per m ----------------
// BK=64, XOR-swizzled staging (linear LDS dest, pre-swizzled global source).
// launch_bounds(256,3): 3 blocks/CU (LDS 96K/160K) for cross-block stage/MFMA overlap.
__global__ __launch_bounds__(256, 3) void gemm_min_kernel(
    const unsigned short* __restrict__ zb, const unsigned short* __restrict__ eb,
    const float* __restrict__ z2, const float* __restrict__ e2,
    unsigned* __restrict__ d2min) {
  __shared__ __align__(16) unsigned short lA[128 * 64];
  __shared__ __align__(16) unsigned short lB[128 * 64];

  const int t = threadIdx.x;
  const int w = t >> 6;
  const int l = t & 63;
  const int wr = w >> 1, wc = w & 1;
  int flat = blockIdx.y * 32 + blockIdx.x;
  int nf = (flat >> 3) + (flat & 7) * 512;
  const int tileM = (nf & 31) * 128;
  const int tileN = (nf >> 5) * 128;
  const int l15 = l & 15;
  const int kgr = l >> 4;

  f32x4 acc[4][4];
#pragma unroll
  for (int i = 0; i < 4; ++i)
#pragma unroll
    for (int j = 0; j < 4; ++j) acc[i][j] = (f32x4){0.f, 0.f, 0.f, 0.f};

#pragma unroll 1
  for (int k0 = 0; k0 < DIM; k0 += 64) {
#pragma unroll
    for (int i = 0; i < 4; ++i) {
      int c = i * 256 + t;
      int row = c >> 3;
      int kc = c & 7;
      int kcs = kc ^ (row & 7);
      int ldsbase = (i * 256 + (t & ~63)) * 8;
      gl2lds16(zb + (size_t)(tileN + row) * DIM + (k0 + kcs * 8), &lA[ldsbase]);
      gl2lds16(eb + (size_t)(tileM + row) * DIM + (k0 + kcs * 8), &lB[ldsbase]);
    }
    __syncthreads();

#pragma unroll
    for (int kk = 0; kk < 2; ++kk) {
      bf16x8 a[4], b[4];
      const int kcr = kk * 4 + kgr;
#pragma unroll
      for (int mi = 0; mi < 4; ++mi) {
        int row = wr * 64 + mi * 16 + l15;
        a[mi] = *(const bf16x8*)&lA[row * 64 + ((kcr ^ (row & 7)) * 8)];
      }
#pragma unroll
      for (int ni = 0; ni < 4; ++ni) {
        int row = wc * 64 + ni * 16 + l15;
        b[ni] = *(const bf16x8*)&lB[row * 64 + ((kcr ^ (row & 7)) * 8)];
      }
#pragma unroll
      for (int mi = 0; mi < 4; ++mi)
#pragma unroll
        for (int ni = 0; ni < 4; ++ni)
          acc[mi][ni] = __builtin_amdgcn_mfma_f32_16x16x32_bf16(a[mi], b[ni], acc[mi][ni], 0, 0, 0);
    }
    __syncthreads();
  }

  float* z2s = (float*)lA;
  if (t < 128) z2s[t] = z2[tileN + t];
  __syncthreads();

#pragma unroll
  for (int ni = 0; ni < 4; ++ni) {
    float v = 3.4e38f;
#pragma unroll
    for (int mi = 0; mi < 4; ++mi)
#pragma unroll
      for (int r = 0; r < 4; ++r) {
        int rloc = wr * 64 + mi * 16 + kgr * 4 + r;
        v = fminf(v, z2s[rloc] - 2.0f * acc[mi][ni][r]);
      }
    v = fminf(v, __shfl_xor(v, 16));
    v = fminf(v, __shfl_xor(v, 32));
    if (l < 16) {
      int m = tileM + wc * 64 + ni * 16 + l;
      float d2 = v + e2[m];
      atomicMin(&d2min[m], __float_as_uint(d2));
    }
  }
}

// ---------------- wise8: bucket-sorted queries in regs + float4 over-scan + tables ----------------
// LDS 76KB (2 blocks/CU). Phase E sorts e VALUES into zs[0:4096] (alias) and pulls
// each thread's 4 queries to registers in sorted-slot order q*1024+t: lanes get
// adjacent sorted queries -> identical slices -> broadcast LDS reads, no divergence.
// Sum over sorted values == sum over e (permutation) -> exact.
__global__ __launch_bounds__(1024) void wise8_kernel(
    const float* __restrict__ zT, const float* __restrict__ eT,
    float* __restrict__ wise_part) {
  extern __shared__ __align__(16) char smem[];
  float* zs = (float*)smem;                        // 16384 f (64K)
  unsigned* zoff = (unsigned*)(smem + 65536);      // 1024 u
  unsigned* pmax = zoff + NB5;                     // 1024 u
  unsigned* psminN = pmax + NB5;                   // 1024 u
  float* esorted = zs;                             // alias zs[0:4096] (phase E only)
  unsigned* eoff = zoff;                           // alias (phase E only)
  __shared__ unsigned scr[16];

  const int d = blockIdx.x, t = threadIdx.x;
  const int lane = t & 63, wid = t >> 6;

  // ---------- phase E: counting-sort e values ----------
  eoff[t] = 0u;
  __syncthreads();
  const float* ec = eT + (size_t)d * M_E;
  float ev4[4];
  int ebk[4];
#pragma unroll
  for (int i = 0; i < 4; ++i) {
    ev4[i] = ec[i * 1024 + t];
    ebk[i] = bucket5(ev4[i]);
    atomicAdd(&eoff[ebk[i]], 1u);
  }
  __syncthreads();
  {  // exclusive sum scan on eoff
    unsigned c = eoff[t];
    unsigned incl = c;
#pragma unroll
    for (int o = 1; o < 64; o <<= 1) {
      unsigned v = __shfl_up(incl, o);
      if (lane >= o) incl += v;
    }
    if (lane == 63) scr[wid] = incl;
    __syncthreads();
    if (t == 0) {
      unsigned run = 0;
#pragma unroll
      for (int i = 0; i < 16; ++i) { unsigned v = scr[i]; scr[i] = run; run += v; }
    }
    __syncthreads();
    unsigned excl = scr[wid] + incl - c;
    __syncthreads();
    eoff[t] = excl;
  }
  __syncthreads();
#pragma unroll
  for (int i = 0; i < 4; ++i) {
    unsigned pos = atomicAdd(&eoff[ebk[i]], 1u);
    esorted[pos] = ev4[i];
  }
  __syncthreads();
  float eq[4];
#pragma unroll
  for (int q = 0; q < 4; ++q) eq[q] = esorted[q * 1024 + t];  // sorted-slot order
  __syncthreads();

  // ---------- phase Z: build bucket-ordered z + tables (overwrites aliases) ----------
  zoff[t] = 0u;
  __syncthreads();

  float zv[16];
  int zbk[16];
  const float4* p = (const float4*)(zT + (size_t)d * N_Z);
#pragma unroll
  for (int i = 0; i < 4; ++i) {
    float4 v = p[i * 1024 + t];
    zv[4 * i + 0] = v.x; zv[4 * i + 1] = v.y; zv[4 * i + 2] = v.z; zv[4 * i + 3] = v.w;
  }
#pragma unroll
  for (int i = 0; i < 16; ++i) {
    zbk[i] = bucket5(zv[i]);
    atomicAdd(&zoff[zbk[i]], 1u);
  }
  __syncthreads();

  {  // exclusive sum scan on zoff
    unsigned c = zoff[t];
    unsigned incl = c;
#pragma unroll
    for (int o = 1; o < 64; o <<= 1) {
      unsigned v = __shfl_up(incl, o);
      if (lane >= o) incl += v;
    }
    if (lane == 63) scr[wid] = incl;
    __syncthreads();
    if (t == 0) {
      unsigned run = 0;
#pragma unroll
      for (int i = 0; i < 16; ++i) { unsigned v = scr[i]; scr[i] = run; run += v; }
    }
    __syncthreads();
    unsigned excl = scr[wid] + incl - c;
    __syncthreads();
    zoff[t] = excl;
  }
  __syncthreads();

#pragma unroll
  for (int i = 0; i < 16; ++i) {
    unsigned pos = atomicAdd(&zoff[zbk[i]], 1u);
    zs[pos] = zv[i];
  }
  __syncthreads();

  // per-bucket min/max from exact slice scan (no over-scan in table build)
  {
    unsigned s0 = t ? zoff[t - 1] : 0u;
    unsigned s1 = zoff[t];
    unsigned mxU = 0u, mnN = 0u;
    for (unsigned j = s0; j < s1; ++j) {
      unsigned u = fmap(zs[j]);
      mxU = max(mxU, u);
      mnN = max(mnN, ~u);
    }
    pmax[t] = mxU;
    psminN[t] = mnN;
  }
  __syncthreads();

  // inclusive prefix-MAX scan on pmax (forward)
  {
    unsigned s = pmax[t];
    unsigned incl = s;
#pragma unroll
    for (int o = 1; o < 64; o <<= 1) {
      unsigned v = __shfl_up(incl, o);
      if (lane >= o) incl = max(incl, v);
    }
    __syncthreads();
    if (lane == 63) scr[wid] = incl;
    __syncthreads();
    if (t == 0) {
      unsigned run = 0;
#pragma unroll
      for (int i = 0; i < 16; ++i) { unsigned v = scr[i]; scr[i] = run; run = max(run, v); }
    }
    __syncthreads();
    pmax[t] = max(scr[wid], incl);
  }
  // inclusive suffix-MIN scan via prefix-max on ~fmap space, reversed index
  {
    int tr = NB5 - 1 - t;
    unsigned s = psminN[tr];
    unsigned incl = s;
#pragma unroll
    for (int o = 1; o < 64; o <<= 1) {
      unsigned v = __shfl_up(incl, o);
      if (lane >= o) incl = max(incl, v);
    }
    __syncthreads();
    if (lane == 63) scr[wid] = incl;
    __syncthreads();
    if (t == 0) {
      unsigned run = 0;
#pragma unroll
      for (int i = 0; i < 16; ++i) { unsigned v = scr[i]; scr[i] = run; run = max(run, v); }
    }
    __syncthreads();
    psminN[tr] = max(scr[wid], incl);
  }
  __syncthreads();

  // ---------- queries from regs: float4 over-scan + 2 table lookups ----------
  float accq = 0.0f;
#pragma unroll 1
  for (int q = 0; q < 4; ++q) {
    float ev = eq[q];
    int b0 = bucket5(ev);
    unsigned s0 = b0 ? zoff[b0 - 1] : 0u;
    unsigned s1 = zoff[b0];
    float best2 = 3.4e38f;
    if (b0 > 0) {
      unsigned u = pmax[b0 - 1];
      if (u) { float dd = funmap(u) - ev; best2 = dd * dd; }
    }
    if (b0 < NB5 - 1) {
      unsigned u = psminN[b0 + 1];
      if (u) { float dd = funmap(~u) - ev; best2 = fminf(best2, dd * dd); }
    }
    for (unsigned j = s0 & ~3u; j < s1; j += 4) {
      float4 zz = *(const float4*)&zs[j];
      float d0 = zz.x - ev, d1 = zz.y - ev;
      float d2 = zz.z - ev, d3 = zz.w - ev;
      best2 = fminf(best2, fminf(fminf(d0 * d0, d1 * d1), fminf(d2 * d2, d3 * d3)));
    }
    accq += best2;
  }

#pragma unroll
  for (int o = 32; o; o >>= 1) accq += __shfl_down(accq, o);
  __syncthreads();
  if (lane == 0) scr[wid] = __float_as_uint(accq);
  __syncthreads();
  if (t == 0) {
    float ssum = 0.0f;
#pragma unroll
    for (int i = 0; i < 16; ++i) ssum += __uint_as_float(scr[i]);
    atomicAdd(&wise_part[d & 63], ssum);
  }
}

// ---------------- final reduce ----------------
__global__ void final_kernel(const unsigned* __restrict__ d2min,
                             const float* __restrict__ wise_part, float* __restrict__ out) {
  __shared__ float red[4];
  int t = threadIdx.x;
  float s = 0.0f;
  for (int m = t; m < M_E; m += 256) s += __uint_as_float(d2min[m]);
#pragma unroll
  for (int off = 32; off; off >>= 1) s += __shfl_down(s, off);
  if ((t & 63) == 0) red[t >> 6] = s;
  __syncthreads();
  if (t == 0) {
    float tot = red[0] + red[1] + red[2] + red[3];
    out[0] = tot / (float)M_E;
    float w = 0.0f;
    for (int i = 0; i < 64; ++i) w += wise_part[i];
    out[1] = w / ((float)M_E * (float)DIM);
  }
}

extern "C" void kernel_launch(void* const* d_in, const int* in_sizes, int n_in,
                              void* d_out, int out_size, void* d_ws, size_t ws_size,
                              hipStream_t stream) {
  const float* z = (const float*)d_in[0];
  const float* e = (const float*)d_in[1];
  float* out = (float*)d_out;

  char* ws = (char*)d_ws;
  unsigned short* zb = (unsigned short*)ws;                 // 8 MiB
  unsigned short* eb = (unsigned short*)(ws + 8388608);     // 2 MiB
  float* z2 = (float*)(ws + 10485760);                      // 64 KiB
  float* e2 = (float*)(ws + 10551296);                      // 16 KiB
  unsigned* d2min = (unsigned*)(ws + 10567680);             // 16 KiB
  float* wise_part = (float*)(ws + 10584064);               // 256 B
  float* zT = (float*)(ws + 11534336);                      // 16 MiB
  float* eT = (float*)(ws + 28311552);                      // 4 MiB -> 32505856

  const size_t LDS_WISE = 65536 + 3 * NB5 * 4;              // 77824 B -> 2 blocks/CU
  static int attr_done = 0;
  if (!attr_done) {
    (void)hipFuncSetAttribute((const void*)wise8_kernel,
                              hipFuncAttributeMaxDynamicSharedMemorySize, (int)LDS_WISE);
    attr_done = 1;
  }

  init_kernel<<<64, 256, 0, stream>>>(d2min, wise_part, z2, e2);
  prep_kernel<<<dim3(N_Z / 32, DIM / 32), dim3(32, 8), 0, stream>>>(z, zT, zb, z2, N_Z);
  prep_kernel<<<dim3(M_E / 32, DIM / 32), dim3(32, 8), 0, stream>>>(e, eT, eb, e2, M_E);
  gemm_min_kernel<<<dim3(32, 128), 256, 0, stream>>>(zb, eb, z2, e2, d2min);
  wise8_kernel<<<DIM, 1024, LDS_WISE, stream>>>(zT, eT, wise_part);
  final_kernel<<<1, 256, 0, stream>>>(d2min, wise_part, out);
}

// Round 11
// 137.501 us; speedup vs baseline: 1.0880x; 1.0880x over previous
//
#include <hip/hip_runtime.h>
#include <hip/hip_bf16.h>

#define N_Z 16384
#define M_E 4096
#define DIM 256
#define NB5 1024                      // wise buckets (monotone map)
#define BMIN (-6.0f)
#define SCALE5 ((float)NB5 / 12.0f)

typedef __bf16 bf16x8 __attribute__((ext_vector_type(8)));
typedef float f32x4 __attribute__((ext_vector_type(4)));

__device__ __forceinline__ unsigned short f2bf(float f) {
  unsigned u = __float_as_uint(f);
  u = (u + 0x7FFFu + ((u >> 16) & 1u)) >> 16;
  return (unsigned short)u;
}

__device__ __forceinline__ void gl2lds16(const void* g, void* s) {
  __builtin_amdgcn_global_load_lds(
      (const __attribute__((address_space(1))) unsigned*)g,
      (__attribute__((address_space(3))) unsigned*)s, 16, 0, 0);
}

// order-preserving float<->uint map
__device__ __forceinline__ unsigned fmap(float f) {
  unsigned u = __float_as_uint(f);
  return (u & 0x80000000u) ? ~u : (u | 0x80000000u);
}
__device__ __forceinline__ float funmap(unsigned u) {
  return __uint_as_float((u & 0x80000000u) ? (u ^ 0x80000000u) : ~u);
}
// MONOTONE bucket map (v<w => bucket(v)<=bucket(w)); exactness needs only monotonicity
__device__ __forceinline__ int bucket5(float v) {
  int b = (int)((v - BMIN) * SCALE5);
  return min(max(b, 0), NB5 - 1);
}

// ---------------- init: d2min=+inf, wise_part=0 (z2/e2 now written directly) ----------------
__global__ void init_kernel(unsigned* __restrict__ d2min, float* __restrict__ wise_part) {
  int i = blockIdx.x * blockDim.x + threadIdx.x;
  if (i < M_E) d2min[i] = 0x7F800000u;
  if (i < 64) wise_part[i] = 0.0f;
}

// ---------------- prep2: one kernel for z AND e; full row-group per block ----------------
// block (32,8), grid (N_Z+M_E)/32. Row sums accumulate in registers across the 8
// col-chunks -> single non-atomic write, no init dependency.
__global__ __launch_bounds__(256) void prep2_kernel(
    const float* __restrict__ z, const float* __restrict__ e,
    float* __restrict__ zT, float* __restrict__ eT,
    unsigned short* __restrict__ zb, unsigned short* __restrict__ eb,
    float* __restrict__ z2, float* __restrict__ e2) {
  __shared__ float tile[32][33];
  int rblk = blockIdx.x * 32;
  const float* in;
  float* outT;
  unsigned short* outB;
  float* rsum;
  int R, r0;
  if (rblk < N_Z) {
    in = z; outT = zT; outB = zb; rsum = z2; R = N_Z; r0 = rblk;
  } else {
    in = e; outT = eT; outB = eb; rsum = e2; R = M_E; r0 = rblk - N_Z;
  }
  int tx = threadIdx.x, ty = threadIdx.y;
  float acc[4] = {0.f, 0.f, 0.f, 0.f};
#pragma unroll 1
  for (int cc = 0; cc < DIM; cc += 32) {
#pragma unroll
    for (int i = 0; i < 4; ++i) {
      int rr = ty + 8 * i;
      float v = in[(size_t)(r0 + rr) * DIM + cc + tx];
      tile[rr][tx] = v;
      outB[(size_t)(r0 + rr) * DIM + cc + tx] = f2bf(v);
      acc[i] += v * v;
    }
    __syncthreads();
#pragma unroll
    for (int i = 0; i < 4; ++i)
      outT[(size_t)(cc + ty + 8 * i) * R + r0 + tx] = tile[tx][ty + 8 * i];
    __syncthreads();
  }
#pragma unroll
  for (int i = 0; i < 4; ++i) {
    float s = acc[i];
#pragma unroll
    for (int o = 1; o < 32; o <<= 1) s += __shfl_xor(s, o);  // xor<32: stays in row group
    if (tx == 0) rsum[r0 + ty + 8 * i] = s;
  }
}

// ---------------- fused bf16 GEMM (z . e^T) + min over n, per m ----------------
// BK=64, XOR-swizzled staging (linear LDS dest, pre-swizzled global source).
// launch_bounds(256,2): (256,3)'s VGPR cap of ~170 regressed ~+9us in R10.
__global__ __launch_bounds__(256, 2) void gemm_min_kernel(
    const unsigned short* __restrict__ zb, const unsigned short* __restrict__ eb,
    const float* __restrict__ z2, const float* __restrict__ e2,
    unsigned* __restrict__ d2min) {
  __shared__ __align__(16) unsigned short lA[128 * 64];
  __shared__ __align__(16) unsigned short lB[128 * 64];

  const int t = threadIdx.x;
  const int w = t >> 6;
  const int l = t & 63;
  const int wr = w >> 1, wc = w & 1;
  int flat = blockIdx.y * 32 + blockIdx.x;
  int nf = (flat >> 3) + (flat & 7) * 512;
  const int tileM = (nf & 31) * 128;
  const int tileN = (nf >> 5) * 128;
  const int l15 = l & 15;
  const int kgr = l >> 4;

  f32x4 acc[4][4];
#pragma unroll
  for (int i = 0; i < 4; ++i)
#pragma unroll
    for (int j = 0; j < 4; ++j) acc[i][j] = (f32x4){0.f, 0.f, 0.f, 0.f};

#pragma unroll 1
  for (int k0 = 0; k0 < DIM; k0 += 64) {
#pragma unroll
    for (int i = 0; i < 4; ++i) {
      int c = i * 256 + t;
      int row = c >> 3;
      int kc = c & 7;
      int kcs = kc ^ (row & 7);
      int ldsbase = (i * 256 + (t & ~63)) * 8;
      gl2lds16(zb + (size_t)(tileN + row) * DIM + (k0 + kcs * 8), &lA[ldsbase]);
      gl2lds16(eb + (size_t)(tileM + row) * DIM + (k0 + kcs * 8), &lB[ldsbase]);
    }
    __syncthreads();

#pragma unroll
    for (int kk = 0; kk < 2; ++kk) {
      bf16x8 a[4], b[4];
      const int kcr = kk * 4 + kgr;
#pragma unroll
      for (int mi = 0; mi < 4; ++mi) {
        int row = wr * 64 + mi * 16 + l15;
        a[mi] = *(const bf16x8*)&lA[row * 64 + ((kcr ^ (row & 7)) * 8)];
      }
#pragma unroll
      for (int ni = 0; ni < 4; ++ni) {
        int row = wc * 64 + ni * 16 + l15;
        b[ni] = *(const bf16x8*)&lB[row * 64 + ((kcr ^ (row & 7)) * 8)];
      }
#pragma unroll
      for (int mi = 0; mi < 4; ++mi)
#pragma unroll
        for (int ni = 0; ni < 4; ++ni)
          acc[mi][ni] = __builtin_amdgcn_mfma_f32_16x16x32_bf16(a[mi], b[ni], acc[mi][ni], 0, 0, 0);
    }
    __syncthreads();
  }

  float* z2s = (float*)lA;
  if (t < 128) z2s[t] = z2[tileN + t];
  __syncthreads();

#pragma unroll
  for (int ni = 0; ni < 4; ++ni) {
    float v = 3.4e38f;
#pragma unroll
    for (int mi = 0; mi < 4; ++mi)
#pragma unroll
      for (int r = 0; r < 4; ++r) {
        int rloc = wr * 64 + mi * 16 + kgr * 4 + r;
        v = fminf(v, z2s[rloc] - 2.0f * acc[mi][ni][r]);
      }
    v = fminf(v, __shfl_xor(v, 16));
    v = fminf(v, __shfl_xor(v, 32));
    if (l < 16) {
      int m = tileM + wc * 64 + ni * 16 + l;
      float d2 = v + e2[m];
      atomicMin(&d2min[m], __float_as_uint(d2));
    }
  }
}

// ---------------- wise8: bucket-sorted queries in regs + float4 over-scan + tables ----------------
// LDS 76KB (2 blocks/CU). Phase E sorts e VALUES into zs[0:4096] (alias) and pulls
// each thread's 4 queries to registers in sorted-slot order q*1024+t: lanes get
// adjacent sorted queries -> identical slices -> broadcast LDS reads, no divergence.
__global__ __launch_bounds__(1024) void wise8_kernel(
    const float* __restrict__ zT, const float* __restrict__ eT,
    float* __restrict__ wise_part) {
  extern __shared__ __align__(16) char smem[];
  float* zs = (float*)smem;                        // 16384 f (64K)
  unsigned* zoff = (unsigned*)(smem + 65536);      // 1024 u
  unsigned* pmax = zoff + NB5;                     // 1024 u
  unsigned* psminN = pmax + NB5;                   // 1024 u
  float* esorted = zs;                             // alias zs[0:4096] (phase E only)
  unsigned* eoff = zoff;                           // alias (phase E only)
  __shared__ unsigned scr[16];

  const int d = blockIdx.x, t = threadIdx.x;
  const int lane = t & 63, wid = t >> 6;

  // ---------- phase E: counting-sort e values ----------
  eoff[t] = 0u;
  __syncthreads();
  const float* ec = eT + (size_t)d * M_E;
  float ev4[4];
  int ebk[4];
#pragma unroll
  for (int i = 0; i < 4; ++i) {
    ev4[i] = ec[i * 1024 + t];
    ebk[i] = bucket5(ev4[i]);
    atomicAdd(&eoff[ebk[i]], 1u);
  }
  __syncthreads();
  {  // exclusive sum scan on eoff
    unsigned c = eoff[t];
    unsigned incl = c;
#pragma unroll
    for (int o = 1; o < 64; o <<= 1) {
      unsigned v = __shfl_up(incl, o);
      if (lane >= o) incl += v;
    }
    if (lane == 63) scr[wid] = incl;
    __syncthreads();
    if (t == 0) {
      unsigned run = 0;
#pragma unroll
      for (int i = 0; i < 16; ++i) { unsigned v = scr[i]; scr[i] = run; run += v; }
    }
    __syncthreads();
    unsigned excl = scr[wid] + incl - c;
    __syncthreads();
    eoff[t] = excl;
  }
  __syncthreads();
#pragma unroll
  for (int i = 0; i < 4; ++i) {
    unsigned pos = atomicAdd(&eoff[ebk[i]], 1u);
    esorted[pos] = ev4[i];
  }
  __syncthreads();
  float eq[4];
#pragma unroll
  for (int q = 0; q < 4; ++q) eq[q] = esorted[q * 1024 + t];  // sorted-slot order
  __syncthreads();

  // ---------- phase Z: build bucket-ordered z + tables (overwrites aliases) ----------
  zoff[t] = 0u;
  __syncthreads();

  float zv[16];
  int zbk[16];
  const float4* p = (const float4*)(zT + (size_t)d * N_Z);
#pragma unroll
  for (int i = 0; i < 4; ++i) {
    float4 v = p[i * 1024 + t];
    zv[4 * i + 0] = v.x; zv[4 * i + 1] = v.y; zv[4 * i + 2] = v.z; zv[4 * i + 3] = v.w;
  }
#pragma unroll
  for (int i = 0; i < 16; ++i) {
    zbk[i] = bucket5(zv[i]);
    atomicAdd(&zoff[zbk[i]], 1u);
  }
  __syncthreads();

  {  // exclusive sum scan on zoff
    unsigned c = zoff[t];
    unsigned incl = c;
#pragma unroll
    for (int o = 1; o < 64; o <<= 1) {
      unsigned v = __shfl_up(incl, o);
      if (lane >= o) incl += v;
    }
    if (lane == 63) scr[wid] = incl;
    __syncthreads();
    if (t == 0) {
      unsigned run = 0;
#pragma unroll
      for (int i = 0; i < 16; ++i) { unsigned v = scr[i]; scr[i] = run; run += v; }
    }
    __syncthreads();
    unsigned excl = scr[wid] + incl - c;
    __syncthreads();
    zoff[t] = excl;
  }
  __syncthreads();

#pragma unroll
  for (int i = 0; i < 16; ++i) {
    unsigned pos = atomicAdd(&zoff[zbk[i]], 1u);
    zs[pos] = zv[i];
  }
  __syncthreads();

  // per-bucket min/max from exact slice scan (no over-scan in table build)
  {
    unsigned s0 = t ? zoff[t - 1] : 0u;
    unsigned s1 = zoff[t];
    unsigned mxU = 0u, mnN = 0u;
    for (unsigned j = s0; j < s1; ++j) {
      unsigned u = fmap(zs[j]);
      mxU = max(mxU, u);
      mnN = max(mnN, ~u);
    }
    pmax[t] = mxU;
    psminN[t] = mnN;
  }
  __syncthreads();

  // inclusive prefix-MAX scan on pmax (forward)
  {
    unsigned s = pmax[t];
    unsigned incl = s;
#pragma unroll
    for (int o = 1; o < 64; o <<= 1) {
      unsigned v = __shfl_up(incl, o);
      if (lane >= o) incl = max(incl, v);
    }
    __syncthreads();
    if (lane == 63) scr[wid] = incl;
    __syncthreads();
    if (t == 0) {
      unsigned run = 0;
#pragma unroll
      for (int i = 0; i < 16; ++i) { unsigned v = scr[i]; scr[i] = run; run = max(run, v); }
    }
    __syncthreads();
    pmax[t] = max(scr[wid], incl);
  }
  // inclusive suffix-MIN scan via prefix-max on ~fmap space, reversed index
  {
    int tr = NB5 - 1 - t;
    unsigned s = psminN[tr];
    unsigned incl = s;
#pragma unroll
    for (int o = 1; o < 64; o <<= 1) {
      unsigned v = __shfl_up(incl, o);
      if (lane >= o) incl = max(incl, v);
    }
    __syncthreads();
    if (lane == 63) scr[wid] = incl;
    __syncthreads();
    if (t == 0) {
      unsigned run = 0;
#pragma unroll
      for (int i = 0; i < 16; ++i) { unsigned v = scr[i]; scr[i] = run; run = max(run, v); }
    }
    __syncthreads();
    psminN[tr] = max(scr[wid], incl);
  }
  __syncthreads();

  // ---------- queries from regs: float4 over-scan + 2 table lookups ----------
  float accq = 0.0f;
#pragma unroll 1
  for (int q = 0; q < 4; ++q) {
    float ev = eq[q];
    int b0 = bucket5(ev);
    unsigned s0 = b0 ? zoff[b0 - 1] : 0u;
    unsigned s1 = zoff[b0];
    float best2 = 3.4e38f;
    if (b0 > 0) {
      unsigned u = pmax[b0 - 1];
      if (u) { float dd = funmap(u) - ev; best2 = dd * dd; }
    }
    if (b0 < NB5 - 1) {
      unsigned u = psminN[b0 + 1];
      if (u) { float dd = funmap(~u) - ev; best2 = fminf(best2, dd * dd); }
    }
    for (unsigned j = s0 & ~3u; j < s1; j += 4) {
      float4 zz = *(const float4*)&zs[j];
      float d0 = zz.x - ev, d1 = zz.y - ev;
      float d2 = zz.z - ev, d3 = zz.w - ev;
      best2 = fminf(best2, fminf(fminf(d0 * d0, d1 * d1), fminf(d2 * d2, d3 * d3)));
    }
    accq += best2;
  }

#pragma unroll
  for (int o = 32; o; o >>= 1) accq += __shfl_down(accq, o);
  __syncthreads();
  if (lane == 0) scr[wid] = __float_as_uint(accq);
  __syncthreads();
  if (t == 0) {
    float ssum = 0.0f;
#pragma unroll
    for (int i = 0; i < 16; ++i) ssum += __uint_as_float(scr[i]);
    atomicAdd(&wise_part[d & 63], ssum);
  }
}

// ---------------- final reduce ----------------
__global__ void final_kernel(const unsigned* __restrict__ d2min,
                             const float* __restrict__ wise_part, float* __restrict__ out) {
  __shared__ float red[4];
  int t = threadIdx.x;
  float s = 0.0f;
  for (int m = t; m < M_E; m += 256) s += __uint_as_float(d2min[m]);
#pragma unroll
  for (int off = 32; off; off >>= 1) s += __shfl_down(s, off);
  if ((t & 63) == 0) red[t >> 6] = s;
  __syncthreads();
  if (t == 0) {
    float tot = red[0] + red[1] + red[2] + red[3];
    out[0] = tot / (float)M_E;
    float w = 0.0f;
    for (int i = 0; i < 64; ++i) w += wise_part[i];
    out[1] = w / ((float)M_E * (float)DIM);
  }
}

extern "C" void kernel_launch(void* const* d_in, const int* in_sizes, int n_in,
                              void* d_out, int out_size, void* d_ws, size_t ws_size,
                              hipStream_t stream) {
  const float* z = (const float*)d_in[0];
  const float* e = (const float*)d_in[1];
  float* out = (float*)d_out;

  char* ws = (char*)d_ws;
  unsigned short* zb = (unsigned short*)ws;                 // 8 MiB
  unsigned short* eb = (unsigned short*)(ws + 8388608);     // 2 MiB
  float* z2 = (float*)(ws + 10485760);                      // 64 KiB
  float* e2 = (float*)(ws + 10551296);                      // 16 KiB
  unsigned* d2min = (unsigned*)(ws + 10567680);             // 16 KiB
  float* wise_part = (float*)(ws + 10584064);               // 256 B
  float* zT = (float*)(ws + 11534336);                      // 16 MiB
  float* eT = (float*)(ws + 28311552);                      // 4 MiB -> 32505856

  const size_t LDS_WISE = 65536 + 3 * NB5 * 4;              // 77824 B -> 2 blocks/CU
  static int attr_done = 0;
  if (!attr_done) {
    (void)hipFuncSetAttribute((const void*)wise8_kernel,
                              hipFuncAttributeMaxDynamicSharedMemorySize, (int)LDS_WISE);
    attr_done = 1;
  }

  init_kernel<<<16, 256, 0, stream>>>(d2min, wise_part);
  prep2_kernel<<<(N_Z + M_E) / 32, dim3(32, 8), 0, stream>>>(z, e, zT, eT, zb, eb, z2, e2);
  gemm_min_kernel<<<dim3(32, 128), 256, 0, stream>>>(zb, eb, z2, e2, d2min);
  wise8_kernel<<<DIM, 1024, LDS_WISE, stream>>>(zT, eT, wise_part);
  final_kernel<<<1, 256, 0, stream>>>(d2min, wise_part, out);
}